// Round 1
// baseline (246.936 us; speedup 1.0000x reference)
//
#include <hip/hip_runtime.h>

// PDELoss: fused 3x3 per-sample stencils + 1/r term + Gauss 3x3 SAME smooth + MSE.
// B=256, H=W=256 f32. Memory-bound: pred (64 MiB) + rhs (62.6 MiB) read once.
// Grid: 256 images x 8 row-strips; block=256 threads (thread = column).
// Rolling 3-row LDS pred buffer; GS_ope row in LDS (guard zeros for SAME pad);
// separable Gauss: horizontal pass from LDS, vertical pass in registers.

#define STRIP 32

__global__ __launch_bounds__(256, 8)
void pde_loss_kernel(const float* __restrict__ pred,   // [B,256,256]
                     const float* __restrict__ rhs,    // [B,254,254]
                     const float* __restrict__ KL,     // [B,3,3]
                     const float* __restrict__ KD,     // [B,3,3]
                     const float* __restrict__ RR,     // [B,256,256] (depends on w only)
                     const float* __restrict__ ZZ,     // [B,256,256] (depends on h only)
                     float* __restrict__ out,          // [1]
                     float inv_n)
{
    constexpr int H = 256, W = 256, OH = 254, OW = 254;
    const int tid   = threadIdx.x;
    const int strip = blockIdx.x & 7;
    const int b     = blockIdx.x >> 3;
    const int o0 = strip * STRIP;
    const int o1 = (o0 + STRIP < OH) ? (o0 + STRIP) : OH;   // last strip: 30 rows

    __shared__ float spred[3][W];   // rolling pred rows, slot = row % 3
    __shared__ float gsbuf[W];      // GS_ope col c at [c+1]; zero guards at [0],[255]

    const size_t ib   = (size_t)b * H * W;
    const float* predb = pred + ib;
    const float* rhsb  = rhs + (size_t)b * OH * OW;

    // per-sample grid spacings (constant across the image by construction)
    const float hr  = RR[ib + W + 2] - RR[ib + W + 1];
    const float hz  = ZZ[ib + 2 * W + 1] - ZZ[ib + W + 1];
    const float hr2 = hr * hr, hz2 = hz * hz;
    const float s   = -2.0f * (hr2 + hz2) / (hr2 * hz2);   // alfa/(hr^2 hz^2)

    // lhs = xcorr(pred,KL) + xcorr(pred,KD)/r[j+1]; GS_ope = s*lhs
    // -> fold into 9 per-column coefficients
    float coef[9];
    {
        float inv_r = 0.0f;
        if (tid < OW) inv_r = 1.0f / RR[ib + W + (tid + 1)];
        const float* kl = KL + b * 9;
        const float* kd = KD + b * 9;
#pragma unroll
        for (int t = 0; t < 9; ++t)
            coef[t] = (kl[t] + kd[t] * inv_r) * s;
    }

    // Prologue: pred rows g0, g0+1 (valid ones). GS row g needs pred rows g..g+2.
    const int g0 = o0 - 1;
    if (g0 >= 0) {
        if (tid < 64)
            ((float4*)spred[g0 % 3])[tid] = ((const float4*)(predb + (size_t)g0 * W))[tid];
    }
    if (tid < 64)
        ((float4*)spred[(g0 + 1) % 3])[tid] = ((const float4*)(predb + (size_t)(g0 + 1) * W))[tid];

    float ghA = 0.0f, ghB = 0.0f;   // horizontal-pass rows g-2, g-1
    float acc = 0.0f;

    for (int g = g0; g <= o1; ++g) {
        const int p = g + 2;
        if (p < H && tid < 64)
            ((float4*)spred[p % 3])[tid] = ((const float4*)(predb + (size_t)p * W))[tid];
        __syncthreads();

        // GS_ope row g (zero outside [0,OH) — SAME padding)
        float gs = 0.0f;
        if (g >= 0 && g < OH && tid < OW) {
            const float* r0 = spred[g % 3];
            const float* r1 = spred[(g + 1) % 3];
            const float* r2 = spred[(g + 2) % 3];
            gs = fmaf(r0[tid],     coef[0],
                 fmaf(r0[tid + 1], coef[1],
                 fmaf(r0[tid + 2], coef[2],
                 fmaf(r1[tid],     coef[3],
                 fmaf(r1[tid + 1], coef[4],
                 fmaf(r1[tid + 2], coef[5],
                 fmaf(r2[tid],     coef[6],
                 fmaf(r2[tid + 1], coef[7],
                      r2[tid + 2] * coef[8]))))))));
        }
        if (tid < OW)       gsbuf[tid + 1] = gs;
        else if (tid == OW) gsbuf[0]   = 0.0f;
        else                gsbuf[W-1] = 0.0f;
        __syncthreads();

        // horizontal [1,2,1]
        float ghC = 0.0f;
        if (tid < OW)
            ghC = gsbuf[tid] + 2.0f * gsbuf[tid + 1] + gsbuf[tid + 2];

        // vertical [1,2,1]/16, emit row i = g-1
        const int i = g - 1;
        if (i >= o0 && i < o1 && tid < OW) {
            const float sm = (ghA + 2.0f * ghB + ghC) * 0.0625f;
            const float d  = sm - rhsb[(size_t)i * OW + tid];
            acc = fmaf(d, d, acc);
        }
        ghA = ghB; ghB = ghC;
    }

    // block reduction: wave shuffle -> LDS -> one atomic per block
#pragma unroll
    for (int off = 32; off > 0; off >>= 1)
        acc += __shfl_down(acc, off, 64);
    __shared__ float wsum[4];
    if ((tid & 63) == 0) wsum[tid >> 6] = acc;
    __syncthreads();
    if (tid == 0) {
        const float t = (wsum[0] + wsum[1]) + (wsum[2] + wsum[3]);
        atomicAdd(out, t * inv_n);
    }
}

extern "C" void kernel_launch(void* const* d_in, const int* in_sizes, int n_in,
                              void* d_out, int out_size, void* d_ws, size_t ws_size,
                              hipStream_t stream) {
    const float* pred = (const float*)d_in[0];
    const float* rhs  = (const float*)d_in[1];
    const float* KL   = (const float*)d_in[2];
    const float* KD   = (const float*)d_in[3];
    const float* RR   = (const float*)d_in[4];
    const float* ZZ   = (const float*)d_in[5];
    // d_in[6] = Gauss kernel: fixed [[1,2,1],[2,4,2],[1,2,1]]/16, hardcoded (separable)
    float* out = (float*)d_out;

    const int B = in_sizes[2] / 9;          // 256
    const float inv_n = 1.0f / ((float)B * 254.0f * 254.0f);

    hipMemsetAsync(out, 0, sizeof(float), stream);   // harness poisons d_out with 0xAA
    pde_loss_kernel<<<dim3(B * 8), dim3(256), 0, stream>>>(pred, rhs, KL, KD, RR, ZZ, out, inv_n);
}

// Round 2
// 223.554 us; speedup vs baseline: 1.1046x; 1.1046x over previous
//
#include <hip/hip_runtime.h>

// PDELoss fused, wave-autonomous version.
// Each 64-lane wave owns one (image, 16-row strip); thread = 4 columns (float4).
// No LDS / no __syncthreads in the hot loop: horizontal halos via __shfl,
// rolling 3-row register window, 1-iteration prefetch distance on pred & rhs.
// GS_ope[c] = sum_{u,v} pred[g+u][c+v] * coef4[u*3+v][c&3], coef folded with
// (KL + KD/r)*alfa/(hr^2 hz^2); Gauss 3x3 separable: horiz from shuffled gs,
// vert via rolling gh registers; MSE accumulated per-thread -> wave shuffle
// reduce -> one atomicAdd per block.

__global__ __launch_bounds__(256, 4)
void pde_loss_kernel(const float* __restrict__ pred,   // [B,256,256]
                     const float* __restrict__ rhs,    // [B,254,254]
                     const float* __restrict__ KL,     // [B,3,3]
                     const float* __restrict__ KD,     // [B,3,3]
                     const float* __restrict__ RR,     // [B,256,256] (col-only)
                     const float* __restrict__ ZZ,     // [B,256,256] (row-only)
                     float* __restrict__ out,
                     float inv_n)
{
    constexpr int H = 256, W = 256, OH = 254, OW = 254;
    const int tid = threadIdx.x;
    const int l   = tid & 63;          // lane
    const int wv  = tid >> 6;          // wave in block
    const int b   = blockIdx.x >> 2;   // image
    const int strip = (blockIdx.x & 3) * 4 + wv;   // 16 strips of 16 rows
    const int o0 = strip * 16;
    const int o1 = (o0 + 16 < OH) ? (o0 + 16) : OH;   // last strip: 14 rows

    const size_t ib = (size_t)b * H * W;
    const float* predb = pred + ib;
    const float* rhsb  = rhs + (size_t)b * OH * OW;

    const float hr  = RR[ib + W + 2] - RR[ib + W + 1];
    const float hz  = ZZ[ib + 2 * W + 1] - ZZ[ib + W + 1];
    const float hr2 = hr * hr, hz2 = hz * hz;
    const float s   = -2.0f * (hr2 + hz2) / (hr2 * hz2);

    // Per-column folded coefficients: c4[t] over the 4 owned cols c0..c0+3
    const int c0 = 4 * l;
    float4 c4[9];
    {
        float4 invr;
        invr.x = 1.0f / RR[ib + W + (c0 + 1)];
        invr.y = 1.0f / RR[ib + W + (c0 + 2)];
        invr.z = 1.0f / RR[ib + W + (c0 + 3)];
        invr.w = 1.0f / RR[ib + W + ((c0 + 4 < W) ? (c0 + 4) : (W - 1))];
        const float* kl = KL + b * 9;
        const float* kd = KD + b * 9;
#pragma unroll
        for (int t = 0; t < 9; ++t) {
            const float a = kl[t] * s, d = kd[t] * s;
            c4[t].x = fmaf(d, invr.x, a);
            c4[t].y = fmaf(d, invr.y, a);
            c4[t].z = fmaf(d, invr.z, a);
            c4[t].w = fmaf(d, invr.w, a);
        }
    }

    // Prologue: rolling pred rows g, g+1, g+2 (as pa, pb, pc) + their halos
    const int g0 = o0 - 1;
    float4 pa = make_float4(0.f, 0.f, 0.f, 0.f), pb, pc;
    if (g0 >= 0) pa = *(const float4*)(predb + (size_t)g0 * W + c0);
    pb = *(const float4*)(predb + (size_t)(g0 + 1) * W + c0);
    pc = *(const float4*)(predb + (size_t)(g0 + 2) * W + c0);
    float nxa = __shfl(pa.x, l + 1, 64), nya = __shfl(pa.y, l + 1, 64);
    float nxb = __shfl(pb.x, l + 1, 64), nyb = __shfl(pb.y, l + 1, 64);

    float4 ghA = make_float4(0.f, 0.f, 0.f, 0.f);
    float4 ghB = make_float4(0.f, 0.f, 0.f, 0.f);
    float2 rc0 = make_float2(0.f, 0.f), rc1 = make_float2(0.f, 0.f);
    float acc = 0.0f;

    for (int g = g0; g <= o1; ++g) {
        // --- prefetch pred row g+3 (consumed next iteration as pc) ---
        float4 pn = make_float4(0.f, 0.f, 0.f, 0.f);
        const int rowp = g + 3;
        if (rowp < H && rowp <= o1 + 2)
            pn = *(const float4*)(predb + (size_t)rowp * W + c0);

        // --- prefetch rhs row g (consumed next iteration at emit i=g) ---
        float2 rn0 = make_float2(0.f, 0.f), rn1 = make_float2(0.f, 0.f);
        if (g >= o0 && g < o1) {
            const float* rrow = rhsb + (size_t)g * OW + c0;
            rn0 = *(const float2*)rrow;
            if (c0 + 2 < OW) rn1 = *(const float2*)(rrow + 2);
        }

        // --- halos for the row newly in position c (loaded last iter) ---
        const float nxc = __shfl(pc.x, l + 1, 64);
        const float nyc = __shfl(pc.y, l + 1, 64);

        // --- GS_ope row g (zero outside [0,OH): SAME padding) ---
        float4 gs = make_float4(0.f, 0.f, 0.f, 0.f);
        if ((unsigned)g < (unsigned)OH) {
#define ROWC(p, nx, ny, t0)                                              \
            gs.x = fmaf(p.x, c4[t0].x, fmaf(p.y, c4[t0+1].x, fmaf(p.z, c4[t0+2].x, gs.x))); \
            gs.y = fmaf(p.y, c4[t0].y, fmaf(p.z, c4[t0+1].y, fmaf(p.w, c4[t0+2].y, gs.y))); \
            gs.z = fmaf(p.z, c4[t0].z, fmaf(p.w, c4[t0+1].z, fmaf(nx,  c4[t0+2].z, gs.z))); \
            gs.w = fmaf(p.w, c4[t0].w, fmaf(nx,  c4[t0+1].w, fmaf(ny,  c4[t0+2].w, gs.w)));
            ROWC(pa, nxa, nya, 0)
            ROWC(pb, nxb, nyb, 3)
            ROWC(pc, nxc, nyc, 6)
#undef ROWC
            if (l == 63) { gs.z = 0.f; gs.w = 0.f; }   // cols 254,255 out of range
        }

        // --- horizontal [1,2,1] ---
        float up = __shfl(gs.w, l - 1, 64);
        const float dn = __shfl(gs.x, l + 1, 64);     // lane 63: garbage, unused
        if (l == 0) up = 0.f;
        float4 gh;
        gh.x = fmaf(2.f, gs.x, up   + gs.y);
        gh.y = fmaf(2.f, gs.y, gs.x + gs.z);
        gh.z = fmaf(2.f, gs.z, gs.y + gs.w);
        gh.w = fmaf(2.f, gs.w, gs.z + dn);

        // --- vertical [1,2,1]/16, emit row i = g-1, MSE accumulate ---
        const int i = g - 1;
        if (i >= o0 && i < o1) {
            const float smx = (ghA.x + 2.f * ghB.x + gh.x) * 0.0625f;
            const float smy = (ghA.y + 2.f * ghB.y + gh.y) * 0.0625f;
            const float smz = (ghA.z + 2.f * ghB.z + gh.z) * 0.0625f;
            const float smw = (ghA.w + 2.f * ghB.w + gh.w) * 0.0625f;
            const float dx = smx - rc0.x;
            const float dy = smy - rc0.y;
            float dz = smz - rc1.x;
            float dw = smw - rc1.y;
            if (c0 + 2 >= OW) { dz = 0.f; dw = 0.f; }   // lane 63 tail cols
            acc = fmaf(dx, dx, acc);
            acc = fmaf(dy, dy, acc);
            acc = fmaf(dz, dz, acc);
            acc = fmaf(dw, dw, acc);
        }

        // --- roll ---
        pa = pb; pb = pc; pc = pn;
        nxa = nxb; nya = nyb; nxb = nxc; nyb = nyc;
        ghA = ghB; ghB = gh;
        rc0 = rn0; rc1 = rn1;
    }

    // wave reduce -> block reduce -> one atomic per block
#pragma unroll
    for (int off = 32; off > 0; off >>= 1)
        acc += __shfl_down(acc, off, 64);
    __shared__ float wsum[4];
    if (l == 0) wsum[wv] = acc;
    __syncthreads();
    if (tid == 0) {
        const float t = (wsum[0] + wsum[1]) + (wsum[2] + wsum[3]);
        atomicAdd(out, t * inv_n);
    }
}

extern "C" void kernel_launch(void* const* d_in, const int* in_sizes, int n_in,
                              void* d_out, int out_size, void* d_ws, size_t ws_size,
                              hipStream_t stream) {
    const float* pred = (const float*)d_in[0];
    const float* rhs  = (const float*)d_in[1];
    const float* KL   = (const float*)d_in[2];
    const float* KD   = (const float*)d_in[3];
    const float* RR   = (const float*)d_in[4];
    const float* ZZ   = (const float*)d_in[5];
    // d_in[6] = Gauss kernel [[1,2,1],[2,4,2],[1,2,1]]/16 — hardcoded, separable
    float* out = (float*)d_out;

    const int B = in_sizes[2] / 9;   // 256
    const float inv_n = 1.0f / ((float)B * 254.0f * 254.0f);

    hipMemsetAsync(out, 0, sizeof(float), stream);
    pde_loss_kernel<<<dim3(B * 4), dim3(256), 0, stream>>>(pred, rhs, KL, KD, RR, ZZ, out, inv_n);
}